// Round 7
// baseline (428.409 us; speedup 1.0000x reference)
//
#include <hip/hip_runtime.h>
#include <hip/hip_bf16.h>

typedef __attribute__((ext_vector_type(8))) short short8;   // 8 x bf16 (4 VGPRs)
typedef __attribute__((ext_vector_type(4))) float f32x4;    // MFMA accumulator

#define N_NODES 8192
#define F 256
#define CAP 256

static __device__ __forceinline__ unsigned short f2bf(float f) {
    unsigned int u = __builtin_bit_cast(unsigned int, f);
    u += 0x7FFFu + ((u >> 16) & 1u);          // round-to-nearest-even
    return (unsigned short)(u >> 16);
}
static __device__ __forceinline__ float bf2f(unsigned short h) {
    unsigned int u = ((unsigned int)h) << 16;
    return __builtin_bit_cast(float, u);
}

// ---------------- K0: W [K][N] fp32 -> Wt [N][K] bf16 ----------------
__global__ __launch_bounds__(256) void k_prep(const float* __restrict__ W,
                                              unsigned short* __restrict__ Wt) {
    int k = blockIdx.x;        // 0..255
    int n = threadIdx.x;       // 0..255, coalesced read of W row k
    Wt[n * 256 + k] = f2bf(W[k * 256 + n]);
}

// ---------------- K1: H = x@W + b (bf16 MFMA), fused s_dst = H @ phi[F:] ----
// block = 128 thr = 2 waves x 16 rows; grid = 8192/32 = 256 -> full CU coverage.
__global__ __launch_bounds__(128) void k_gemm(const float* __restrict__ x,
                                              const float* __restrict__ bias,
                                              const float* __restrict__ phi,
                                              const unsigned short* __restrict__ Wt,
                                              unsigned short* __restrict__ H,
                                              float* __restrict__ s_dst) {
    const int tid  = threadIdx.x;
    const int wave = tid >> 6;    // 0..1
    const int lane = tid & 63;
    const int lrow = lane & 15;   // A row / B col / C col
    const int lk   = lane >> 4;   // k-group (8 consecutive k) / C row-group
    const int r0   = blockIdx.x * 32 + wave * 16;

    f32x4 acc[16];
#pragma unroll
    for (int n = 0; n < 16; ++n) acc[n] = (f32x4){0.f, 0.f, 0.f, 0.f};

#pragma unroll
    for (int k0 = 0; k0 < 256; k0 += 32) {
        const f32x4* ap = (const f32x4*)(x + (size_t)(r0 + lrow) * 256 + k0 + lk * 8);
        f32x4 a0 = __builtin_nontemporal_load(ap);
        f32x4 a1 = __builtin_nontemporal_load(ap + 1);
        short8 a;
        a[0] = (short)f2bf(a0[0]); a[1] = (short)f2bf(a0[1]);
        a[2] = (short)f2bf(a0[2]); a[3] = (short)f2bf(a0[3]);
        a[4] = (short)f2bf(a1[0]); a[5] = (short)f2bf(a1[1]);
        a[6] = (short)f2bf(a1[2]); a[7] = (short)f2bf(a1[3]);
#pragma unroll
        for (int n = 0; n < 16; ++n) {
            short8 b = *(const short8*)(Wt + (size_t)(n * 16 + lrow) * 256 + k0 + lk * 8);
            acc[n] = __builtin_amdgcn_mfma_f32_16x16x32_bf16(a, b, acc[n], 0, 0, 0);
        }
    }

    float sd[4] = {0.f, 0.f, 0.f, 0.f};
#pragma unroll
    for (int n = 0; n < 16; ++n) {
        int c = n * 16 + lrow;
        float bv = bias[c];
        float ph = phi[256 + c];          // phi[F:, 0]
#pragma unroll
        for (int i = 0; i < 4; ++i) {
            int r = r0 + lk * 4 + i;      // C row = (lane>>4)*4 + reg
            float h = acc[n][i] + bv;
            H[(size_t)r * 256 + c] = f2bf(h);
            sd[i] += h * ph;
        }
    }
#pragma unroll
    for (int m = 1; m < 16; m <<= 1) {
#pragma unroll
        for (int i = 0; i < 4; ++i) sd[i] += __shfl_xor(sd[i], m, 64);
    }
    if (lrow == 0) {
#pragma unroll
        for (int i = 0; i < 4; ++i) s_dst[r0 + lk * 4 + i] = sd[i];
    }
}

// ---------------- K2: one WAVE per row; branchless ballot compaction -------
__global__ __launch_bounds__(256) void k_attn(const float* __restrict__ adj,
                                              const unsigned short* __restrict__ H,
                                              const float* __restrict__ s_dst,
                                              float* __restrict__ out) {
    __shared__ int  s_idx[4][CAP];
    __shared__ int2 s_pk[4][CAP];      // {col, bits(w)}

    const int tid  = threadIdx.x;
    const int wave = tid >> 6;
    const int lane = tid & 63;
    const int i    = (blockIdx.x << 2) | wave;

    // Phase 1: stream 32KB adj row (nontemporal, keeps H in L2), compact.
    const f32x4* __restrict__ arow = (const f32x4*)(adj + (size_t)i * N_NODES);
    int cnt = 0;
#pragma unroll 8
    for (int c = 0; c < 32; ++c) {
        int v4 = (c << 6) | lane;
        f32x4 v = __builtin_nontemporal_load(arow + v4);
        int col = v4 << 2;
        bool a0 = (v[0] != 0.f) || (col + 0 == i);
        bool a1 = (v[1] != 0.f) || (col + 1 == i);
        bool a2 = (v[2] != 0.f) || (col + 2 == i);
        bool a3 = (v[3] != 0.f) || (col + 3 == i);
        unsigned long long b0 = __ballot(a0);
        unsigned long long b1 = __ballot(a1);
        unsigned long long b2 = __ballot(a2);
        unsigned long long b3 = __ballot(a3);
        int base = cnt;
        if (a0) {
            int off = __builtin_amdgcn_mbcnt_hi((unsigned)(b0 >> 32),
                      __builtin_amdgcn_mbcnt_lo((unsigned)b0, 0u));
            s_idx[wave][base + off] = col;
        }
        base += (int)__popcll(b0);
        if (a1) {
            int off = __builtin_amdgcn_mbcnt_hi((unsigned)(b1 >> 32),
                      __builtin_amdgcn_mbcnt_lo((unsigned)b1, 0u));
            s_idx[wave][base + off] = col + 1;
        }
        base += (int)__popcll(b1);
        if (a2) {
            int off = __builtin_amdgcn_mbcnt_hi((unsigned)(b2 >> 32),
                      __builtin_amdgcn_mbcnt_lo((unsigned)b2, 0u));
            s_idx[wave][base + off] = col + 2;
        }
        base += (int)__popcll(b2);
        if (a3) {
            int off = __builtin_amdgcn_mbcnt_hi((unsigned)(b3 >> 32),
                      __builtin_amdgcn_mbcnt_lo((unsigned)b3, 0u));
            s_idx[wave][base + off] = col + 3;
        }
        base += (int)__popcll(b3);
        cnt = base;
    }
    asm volatile("s_waitcnt lgkmcnt(0)" ::: "memory");

    // Phase 2: m = max_j s_dst[j] over active set (wave shuffle reduce)
    float mv = -3e38f;
    for (int t = lane; t < cnt; t += 64) {
        int j = s_idx[wave][t];
        float sv = s_dst[j];
        s_pk[wave][t].x = j;
        s_pk[wave][t].y = __float_as_int(sv);
        mv = fmaxf(mv, sv);
    }
#pragma unroll
    for (int d = 32; d; d >>= 1) mv = fmaxf(mv, __shfl_xor(mv, d, 64));
    asm volatile("s_waitcnt lgkmcnt(0)" ::: "memory");

    // Phase 3: w = exp(s - m), Z = sum; pad list to multiple of 8 with w=0
    float zv = 0.f;
    for (int t = lane; t < cnt; t += 64) {
        int2 e = s_pk[wave][t];
        float w = __expf(__int_as_float(e.y) - mv);
        s_pk[wave][t].y = __float_as_int(w);
        zv += w;
    }
#pragma unroll
    for (int d = 32; d; d >>= 1) zv += __shfl_xor(zv, d, 64);
    const float zinv = 1.0f / zv;

    const int P8  = (cnt + 7) & ~7;
    if (lane < P8 - cnt) s_pk[wave][cnt + lane] = make_int2(i, 0);  // w = +0.0f
    asm volatile("s_waitcnt lgkmcnt(0)" ::: "memory");

    // Phase 4: each lane owns 4 features; 8 edges per step for MLP depth
    float a0 = 0.f, a1 = 0.f, a2 = 0.f, a3 = 0.f;
    const unsigned short* __restrict__ hb = H + (lane << 2);
    for (int t = 0; t < P8; t += 8) {
#pragma unroll
        for (int u = 0; u < 8; ++u) {
            int2 e = s_pk[wave][t + u];
            float w = __int_as_float(e.y);
            short4 hv = *(const short4*)(hb + (size_t)e.x * F);
            a0 = fmaf(w, bf2f((unsigned short)hv.x), a0);
            a1 = fmaf(w, bf2f((unsigned short)hv.y), a1);
            a2 = fmaf(w, bf2f((unsigned short)hv.z), a2);
            a3 = fmaf(w, bf2f((unsigned short)hv.w), a3);
        }
    }
    f32x4 o;
    o[0] = a0 * zinv; o[1] = a1 * zinv; o[2] = a2 * zinv; o[3] = a3 * zinv;
    o[0] = (o[0] >= 0.f) ? o[0] : 0.01f * o[0];
    o[1] = (o[1] >= 0.f) ? o[1] : 0.01f * o[1];
    o[2] = (o[2] >= 0.f) ? o[2] : 0.01f * o[2];
    o[3] = (o[3] >= 0.f) ? o[3] : 0.01f * o[3];
    __builtin_nontemporal_store(o, (f32x4*)(out + (size_t)i * F + (lane << 2)));
}

extern "C" void kernel_launch(void* const* d_in, const int* in_sizes, int n_in,
                              void* d_out, int out_size, void* d_ws, size_t ws_size,
                              hipStream_t stream) {
    const float* adj  = (const float*)d_in[0];
    const float* x    = (const float*)d_in[1];
    const float* W    = (const float*)d_in[2];
    const float* bias = (const float*)d_in[3];
    const float* phi  = (const float*)d_in[4];
    float* out = (float*)d_out;

    char* ws = (char*)d_ws;
    unsigned short* Wt = (unsigned short*)ws;                       // 128 KB
    unsigned short* H  = (unsigned short*)(ws + (131072));          // 4 MB
    float* s_dst       = (float*)(ws + 131072 + 4194304);           // 32 KB

    hipLaunchKernelGGL(k_prep, dim3(256),          dim3(256), 0, stream, W, Wt);
    hipLaunchKernelGGL(k_gemm, dim3(N_NODES / 32), dim3(128), 0, stream,
                       x, bias, phi, Wt, H, s_dst);
    // DIAGNOSTIC (this round only): k_attn launched TWICE. It is idempotent
    // (reads adj/H/s_dst, rewrites identical out), so correctness is
    // unchanged and dur_us_delta vs previous round == T(k_attn) measured
    // inside the exact replay environment.
    hipLaunchKernelGGL(k_attn, dim3(N_NODES / 4),  dim3(256), 0, stream,
                       adj, H, s_dst, out);
    hipLaunchKernelGGL(k_attn, dim3(N_NODES / 4),  dim3(256), 0, stream,
                       adj, H, s_dst, out);
}

// Round 8
// 369.817 us; speedup vs baseline: 1.1584x; 1.1584x over previous
//
#include <hip/hip_runtime.h>
#include <hip/hip_bf16.h>

typedef __attribute__((ext_vector_type(8))) short short8;   // 8 x bf16 (4 VGPRs)
typedef __attribute__((ext_vector_type(4))) float f32x4;    // MFMA accumulator

#define N_NODES 8192
#define F 256
#define CAP 256

static __device__ __forceinline__ unsigned short f2bf(float f) {
    unsigned int u = __builtin_bit_cast(unsigned int, f);
    u += 0x7FFFu + ((u >> 16) & 1u);          // round-to-nearest-even
    return (unsigned short)(u >> 16);
}
static __device__ __forceinline__ float bf2f(unsigned short h) {
    unsigned int u = ((unsigned int)h) << 16;
    return __builtin_bit_cast(float, u);
}

// ---------------- K0: W [K][N] fp32 -> Wt [N][K] bf16 ----------------
__global__ __launch_bounds__(256) void k_prep(const float* __restrict__ W,
                                              unsigned short* __restrict__ Wt) {
    int k = blockIdx.x;        // 0..255
    int n = threadIdx.x;       // 0..255, coalesced read of W row k
    Wt[n * 256 + k] = f2bf(W[k * 256 + n]);
}

// ---------------- K1: H = x@W + b (bf16 MFMA), fused s_dst = H @ phi[F:] ----
// block = 128 thr = 2 waves x 16 rows; grid = 8192/32 = 256 -> full CU coverage.
__global__ __launch_bounds__(128) void k_gemm(const float* __restrict__ x,
                                              const float* __restrict__ bias,
                                              const float* __restrict__ phi,
                                              const unsigned short* __restrict__ Wt,
                                              unsigned short* __restrict__ H,
                                              float* __restrict__ s_dst) {
    const int tid  = threadIdx.x;
    const int wave = tid >> 6;    // 0..1
    const int lane = tid & 63;
    const int lrow = lane & 15;   // A row / B col / C col
    const int lk   = lane >> 4;   // k-group (8 consecutive k) / C row-group
    const int r0   = blockIdx.x * 32 + wave * 16;

    f32x4 acc[16];
#pragma unroll
    for (int n = 0; n < 16; ++n) acc[n] = (f32x4){0.f, 0.f, 0.f, 0.f};

#pragma unroll
    for (int k0 = 0; k0 < 256; k0 += 32) {
        const f32x4* ap = (const f32x4*)(x + (size_t)(r0 + lrow) * 256 + k0 + lk * 8);
        f32x4 a0 = __builtin_nontemporal_load(ap);
        f32x4 a1 = __builtin_nontemporal_load(ap + 1);
        short8 a;
        a[0] = (short)f2bf(a0[0]); a[1] = (short)f2bf(a0[1]);
        a[2] = (short)f2bf(a0[2]); a[3] = (short)f2bf(a0[3]);
        a[4] = (short)f2bf(a1[0]); a[5] = (short)f2bf(a1[1]);
        a[6] = (short)f2bf(a1[2]); a[7] = (short)f2bf(a1[3]);
#pragma unroll
        for (int n = 0; n < 16; ++n) {
            short8 b = *(const short8*)(Wt + (size_t)(n * 16 + lrow) * 256 + k0 + lk * 8);
            acc[n] = __builtin_amdgcn_mfma_f32_16x16x32_bf16(a, b, acc[n], 0, 0, 0);
        }
    }

    float sd[4] = {0.f, 0.f, 0.f, 0.f};
#pragma unroll
    for (int n = 0; n < 16; ++n) {
        int c = n * 16 + lrow;
        float bv = bias[c];
        float ph = phi[256 + c];          // phi[F:, 0]
#pragma unroll
        for (int i = 0; i < 4; ++i) {
            int r = r0 + lk * 4 + i;      // C row = (lane>>4)*4 + reg
            float h = acc[n][i] + bv;
            H[(size_t)r * 256 + c] = f2bf(h);
            sd[i] += h * ph;
        }
    }
#pragma unroll
    for (int m = 1; m < 16; m <<= 1) {
#pragma unroll
        for (int i = 0; i < 4; ++i) sd[i] += __shfl_xor(sd[i], m, 64);
    }
    if (lrow == 0) {
#pragma unroll
        for (int i = 0; i < 4; ++i) s_dst[r0 + lk * 4 + i] = sd[i];
    }
}

// ---------------- K2: one WAVE per row; branchless ballot compaction -------
__global__ __launch_bounds__(256) void k_attn(const float* __restrict__ adj,
                                              const unsigned short* __restrict__ H,
                                              const float* __restrict__ s_dst,
                                              float* __restrict__ out) {
    __shared__ int  s_idx[4][CAP];
    __shared__ int2 s_pk[4][CAP];      // {col, bits(w)}

    const int tid  = threadIdx.x;
    const int wave = tid >> 6;
    const int lane = tid & 63;
    const int i    = (blockIdx.x << 2) | wave;

    // Phase 1: stream 32KB adj row (nontemporal, keeps H in L2), compact.
    const f32x4* __restrict__ arow = (const f32x4*)(adj + (size_t)i * N_NODES);
    int cnt = 0;
#pragma unroll 8
    for (int c = 0; c < 32; ++c) {
        int v4 = (c << 6) | lane;
        f32x4 v = __builtin_nontemporal_load(arow + v4);
        int col = v4 << 2;
        bool a0 = (v[0] != 0.f) || (col + 0 == i);
        bool a1 = (v[1] != 0.f) || (col + 1 == i);
        bool a2 = (v[2] != 0.f) || (col + 2 == i);
        bool a3 = (v[3] != 0.f) || (col + 3 == i);
        unsigned long long b0 = __ballot(a0);
        unsigned long long b1 = __ballot(a1);
        unsigned long long b2 = __ballot(a2);
        unsigned long long b3 = __ballot(a3);
        int base = cnt;
        if (a0) {
            int off = __builtin_amdgcn_mbcnt_hi((unsigned)(b0 >> 32),
                      __builtin_amdgcn_mbcnt_lo((unsigned)b0, 0u));
            s_idx[wave][base + off] = col;
        }
        base += (int)__popcll(b0);
        if (a1) {
            int off = __builtin_amdgcn_mbcnt_hi((unsigned)(b1 >> 32),
                      __builtin_amdgcn_mbcnt_lo((unsigned)b1, 0u));
            s_idx[wave][base + off] = col + 1;
        }
        base += (int)__popcll(b1);
        if (a2) {
            int off = __builtin_amdgcn_mbcnt_hi((unsigned)(b2 >> 32),
                      __builtin_amdgcn_mbcnt_lo((unsigned)b2, 0u));
            s_idx[wave][base + off] = col + 2;
        }
        base += (int)__popcll(b2);
        if (a3) {
            int off = __builtin_amdgcn_mbcnt_hi((unsigned)(b3 >> 32),
                      __builtin_amdgcn_mbcnt_lo((unsigned)b3, 0u));
            s_idx[wave][base + off] = col + 3;
        }
        base += (int)__popcll(b3);
        cnt = base;
    }
    asm volatile("s_waitcnt lgkmcnt(0)" ::: "memory");

    // Phase 2: m = max_j s_dst[j] over active set (wave shuffle reduce)
    float mv = -3e38f;
    for (int t = lane; t < cnt; t += 64) {
        int j = s_idx[wave][t];
        float sv = s_dst[j];
        s_pk[wave][t].x = j;
        s_pk[wave][t].y = __float_as_int(sv);
        mv = fmaxf(mv, sv);
    }
#pragma unroll
    for (int d = 32; d; d >>= 1) mv = fmaxf(mv, __shfl_xor(mv, d, 64));
    asm volatile("s_waitcnt lgkmcnt(0)" ::: "memory");

    // Phase 3: w = exp(s - m), Z = sum; pad list to multiple of 8 with w=0
    float zv = 0.f;
    for (int t = lane; t < cnt; t += 64) {
        int2 e = s_pk[wave][t];
        float w = __expf(__int_as_float(e.y) - mv);
        s_pk[wave][t].y = __float_as_int(w);
        zv += w;
    }
#pragma unroll
    for (int d = 32; d; d >>= 1) zv += __shfl_xor(zv, d, 64);
    const float zinv = 1.0f / zv;

    const int P8  = (cnt + 7) & ~7;
    if (lane < P8 - cnt) s_pk[wave][cnt + lane] = make_int2(i, 0);  // w = +0.0f
    asm volatile("s_waitcnt lgkmcnt(0)" ::: "memory");

    // Phase 4: each lane owns 4 features; 8 edges per step for MLP depth
    float a0 = 0.f, a1 = 0.f, a2 = 0.f, a3 = 0.f;
    const unsigned short* __restrict__ hb = H + (lane << 2);
    for (int t = 0; t < P8; t += 8) {
#pragma unroll
        for (int u = 0; u < 8; ++u) {
            int2 e = s_pk[wave][t + u];
            float w = __int_as_float(e.y);
            short4 hv = *(const short4*)(hb + (size_t)e.x * F);
            a0 = fmaf(w, bf2f((unsigned short)hv.x), a0);
            a1 = fmaf(w, bf2f((unsigned short)hv.y), a1);
            a2 = fmaf(w, bf2f((unsigned short)hv.z), a2);
            a3 = fmaf(w, bf2f((unsigned short)hv.w), a3);
        }
    }
    f32x4 o;
    o[0] = a0 * zinv; o[1] = a1 * zinv; o[2] = a2 * zinv; o[3] = a3 * zinv;
    o[0] = (o[0] >= 0.f) ? o[0] : 0.01f * o[0];
    o[1] = (o[1] >= 0.f) ? o[1] : 0.01f * o[1];
    o[2] = (o[2] >= 0.f) ? o[2] : 0.01f * o[2];
    o[3] = (o[3] >= 0.f) ? o[3] : 0.01f * o[3];
    __builtin_nontemporal_store(o, (f32x4*)(out + (size_t)i * F + (lane << 2)));
}

extern "C" void kernel_launch(void* const* d_in, const int* in_sizes, int n_in,
                              void* d_out, int out_size, void* d_ws, size_t ws_size,
                              hipStream_t stream) {
    const float* adj  = (const float*)d_in[0];
    const float* x    = (const float*)d_in[1];
    const float* W    = (const float*)d_in[2];
    const float* bias = (const float*)d_in[3];
    const float* phi  = (const float*)d_in[4];
    float* out = (float*)d_out;

    char* ws = (char*)d_ws;
    unsigned short* Wt = (unsigned short*)ws;                       // 128 KB
    unsigned short* H  = (unsigned short*)(ws + (131072));          // 4 MB
    float* s_dst       = (float*)(ws + 131072 + 4194304);           // 32 KB

    hipLaunchKernelGGL(k_prep, dim3(256),          dim3(256), 0, stream, W, Wt);
    hipLaunchKernelGGL(k_gemm, dim3(N_NODES / 32), dim3(128), 0, stream,
                       x, bias, phi, Wt, H, s_dst);
    // Single k_attn launch (r7's double-launch was a timing diagnostic:
    // T(k_attn) = 58 us measured, ~= its 268MB-adj-stream BW floor).
    hipLaunchKernelGGL(k_attn, dim3(N_NODES / 4),  dim3(256), 0, stream,
                       adj, H, s_dst, out);
}